// Round 4
// baseline (33.932 us; speedup 1.0000x reference)
//
#include <hip/hip_runtime.h>
#include <math.h>

#define NPTS 4096
#define BLOCK 256
#define PTS4 (NPTS / 2)              // 2048 float4 (2 points each)
#define ITERS (PTS4 / BLOCK)         // 8 float4 per thread
#define REG_ITERS 4                  // 4 in registers (16 VGPR)
#define LDS_ITERS (ITERS - REG_ITERS) // 4 in LDS (16 KiB)

typedef float f4 __attribute__((ext_vector_type(4)));

// Hybrid staging: half the points in registers, half in LDS (thread-private
// slots -> no barrier, no cross-thread sharing). VGPR ~50 < 64 so (256,8)
// truly yields 8 blocks/CU = 32 waves/CU; LDS 16.7 KiB also allows 8.
// Points are streamed with nontemporal loads (never reused; don't churn L2).
__global__ __launch_bounds__(BLOCK, 8) void geo_mlp_kernel(
    const float* __restrict__ points,  // (B, N, 2)
    const float* __restrict__ W1,      // (10, 64)
    const float* __restrict__ b1,      // (64)
    const float* __restrict__ W2,      // (64, 32)
    const float* __restrict__ b2,      // (32)
    float* __restrict__ out)           // (B, 32)
{
    __shared__ f4 pl[LDS_ITERS * BLOCK];  // 16 KiB point stage
    __shared__ float wred[4][9];          // per-wave partials
    __shared__ float h[64];               // hidden layer

    const int tid  = threadIdx.x;
    const int lane = tid & 63;
    const int wave = tid >> 6;
    const int b    = blockIdx.x;

    const f4* __restrict__ src = (const f4*)(points + (size_t)b * NPTS * 2);

    float minx =  INFINITY, miny =  INFINITY;
    float maxx = -INFINITY, maxy = -INFINITY;
    float sx = 0.f, sy = 0.f, sxx = 0.f, syy = 0.f;

    f4 p[REG_ITERS];

    // ---- single HBM pass: nontemporal stream -> regs + LDS ----
    #pragma unroll
    for (int i = 0; i < ITERS; ++i) {
        f4 v = __builtin_nontemporal_load(&src[tid + i * BLOCK]);
        if (i < REG_ITERS) p[i] = v;
        else               pl[tid + (i - REG_ITERS) * BLOCK] = v;
        minx = fminf(minx, fminf(v.x, v.z));
        maxx = fmaxf(maxx, fmaxf(v.x, v.z));
        miny = fminf(miny, fminf(v.y, v.w));
        maxy = fmaxf(maxy, fmaxf(v.y, v.w));
        sx += v.x + v.z;
        sy += v.y + v.w;
        sxx = fmaf(v.x, v.x, sxx); sxx = fmaf(v.z, v.z, sxx);
        syy = fmaf(v.y, v.y, syy); syy = fmaf(v.w, v.w, syy);
    }

    // wave (64-lane) butterfly reduction
    #pragma unroll
    for (int off = 32; off > 0; off >>= 1) {
        minx = fminf(minx, __shfl_down(minx, off));
        maxx = fmaxf(maxx, __shfl_down(maxx, off));
        miny = fminf(miny, __shfl_down(miny, off));
        maxy = fmaxf(maxy, __shfl_down(maxy, off));
        sx  += __shfl_down(sx,  off);
        sy  += __shfl_down(sy,  off);
        sxx += __shfl_down(sxx, off);
        syy += __shfl_down(syy, off);
    }
    if (lane == 0) {
        wred[wave][0] = minx; wred[wave][1] = maxx;
        wred[wave][2] = miny; wred[wave][3] = maxy;
        wred[wave][4] = sx;   wred[wave][5] = sy;
        wred[wave][6] = sxx;  wred[wave][7] = syy;
    }
    __syncthreads();

    // all threads combine the 4 wave partials (broadcast LDS reads)
    float fminx = fminf(fminf(wred[0][0], wred[1][0]), fminf(wred[2][0], wred[3][0]));
    float fmaxx = fmaxf(fmaxf(wred[0][1], wred[1][1]), fmaxf(wred[2][1], wred[3][1]));
    float fminy = fminf(fminf(wred[0][2], wred[1][2]), fminf(wred[2][2], wred[3][2]));
    float fmaxy = fmaxf(fmaxf(wred[0][3], wred[1][3]), fmaxf(wred[2][3], wred[3][3]));
    float fsx  = (wred[0][4] + wred[1][4]) + (wred[2][4] + wred[3][4]);
    float fsy  = (wred[0][5] + wred[1][5]) + (wred[2][5] + wred[3][5]);
    float fsxx = (wred[0][6] + wred[1][6]) + (wred[2][6] + wred[3][6]);
    float fsyy = (wred[0][7] + wred[1][7]) + (wred[2][7] + wred[3][7]);

    const float invN = 1.0f / (float)NPTS;
    const float cx = fsx * invN;
    const float cy = fsy * invN;

    // ---- pass 2: distances from regs + LDS (sum(d) only;
    //      sum(d^2) = sxx + syy - N*(cx^2+cy^2) analytically) ----
    float sd = 0.f;
    #pragma unroll
    for (int i = 0; i < REG_ITERS; ++i) {
        f4 v = p[i];
        float dx0 = v.x - cx, dy0 = v.y - cy;
        float dx1 = v.z - cx, dy1 = v.w - cy;
        sd += sqrtf(fmaf(dx0, dx0, dy0 * dy0));
        sd += sqrtf(fmaf(dx1, dx1, dy1 * dy1));
    }
    #pragma unroll
    for (int k = 0; k < LDS_ITERS; ++k) {
        f4 v = pl[tid + k * BLOCK];
        float dx0 = v.x - cx, dy0 = v.y - cy;
        float dx1 = v.z - cx, dy1 = v.w - cy;
        sd += sqrtf(fmaf(dx0, dx0, dy0 * dy0));
        sd += sqrtf(fmaf(dx1, dx1, dy1 * dy1));
    }
    #pragma unroll
    for (int off = 32; off > 0; off >>= 1)
        sd += __shfl_down(sd, off);
    if (lane == 0)
        wred[wave][8] = sd;
    __syncthreads();

    // ---- MLP layer 1: 64 threads, each one hidden unit ----
    if (tid < 64) {
        float fsd = (wred[0][8] + wred[1][8]) + (wred[2][8] + wred[3][8]);
        float dist_mean = fsd * invN;
        float ed2 = (fsxx + fsyy) * invN - (cx * cx + cy * cy);  // E[d^2]
        float dist_std  = sqrtf(fmaxf(ed2 - dist_mean * dist_mean, 0.f));
        float stdx = sqrtf(fmaxf(fsxx * invN - cx * cx, 0.f));
        float stdy = sqrtf(fmaxf(fsyy * invN - cy * cy, 0.f));

        float g[10];
        g[0] = (fminx + fmaxx) * 0.5f;   // bbox_center.x
        g[1] = (fminy + fmaxy) * 0.5f;   // bbox_center.y
        g[2] = fmaxx - fminx;            // bbox_size.x
        g[3] = fmaxy - fminy;            // bbox_size.y
        g[4] = cx;                       // centroid.x
        g[5] = cy;                       // centroid.y
        g[6] = stdx;                     // std.x
        g[7] = stdy;                     // std.y
        g[8] = dist_mean;
        g[9] = dist_std;

        float acc = b1[tid];             // weights: normal cached loads
        #pragma unroll
        for (int i = 0; i < 10; ++i)
            acc = fmaf(g[i], W1[i * 64 + tid], acc);
        h[tid] = fmaxf(acc, 0.f);
    }
    __syncthreads();

    // ---- MLP layer 2: 32 threads, each one output unit ----
    if (tid < 32) {
        float acc = b2[tid];
        #pragma unroll
        for (int i = 0; i < 64; ++i)
            acc = fmaf(h[i], W2[i * 32 + tid], acc);
        out[(size_t)b * 32 + tid] = fmaxf(acc, 0.f);
    }
}

extern "C" void kernel_launch(void* const* d_in, const int* in_sizes, int n_in,
                              void* d_out, int out_size, void* d_ws, size_t ws_size,
                              hipStream_t stream) {
    const float* points = (const float*)d_in[0];
    const float* W1     = (const float*)d_in[1];
    const float* b1     = (const float*)d_in[2];
    const float* W2     = (const float*)d_in[3];
    const float* b2     = (const float*)d_in[4];
    float* out          = (float*)d_out;

    const int B = in_sizes[0] / (NPTS * 2);   // 4096
    geo_mlp_kernel<<<B, BLOCK, 0, stream>>>(points, W1, b1, W2, b2, out);
}

// Round 6
// 28.774 us; speedup vs baseline: 1.1793x; 1.1793x over previous
//
#include <hip/hip_runtime.h>
#include <math.h>

#define NPTS 4096
#define BLOCK 256
#define PTS4 (NPTS / 2)            // 2048 float4 (2 points each)
#define ITERS (PTS4 / BLOCK)       // 8

// R1 structure (LDS point stage, 4 blocks/CU) + weight hoisting:
// wave 0 preloads the whole MLP into registers at kernel START so the
// weight-load latency hides under the 32 KiB point stream, and the MLP
// epilogue is wave-synchronous (no tail global loads, one less barrier).
__global__ __launch_bounds__(BLOCK, 4) void geo_mlp_kernel(
    const float* __restrict__ points,  // (B, N, 2)
    const float* __restrict__ W1,      // (10, 64)
    const float* __restrict__ b1,      // (64)
    const float* __restrict__ W2,      // (64, 32)
    const float* __restrict__ b2,      // (32)
    float* __restrict__ out)           // (B, 32)
{
    __shared__ float4 pts[PTS4];       // 32 KiB point stage
    __shared__ float wred[4][9];       // per-wave partials
    __shared__ float h[64];            // hidden layer

    const int tid  = threadIdx.x;
    const int lane = tid & 63;
    const int wave = tid >> 6;
    const int b    = blockIdx.x;

    // ---- wave 0: preload MLP weights into registers (issue EARLY) ----
    float w1r[10];                     // W1[:, lane]
    float w2r[32];                     // W2[rbase..rbase+31, lane&31]
    float b1r = 0.f, b2r = 0.f;
    const int col   = lane & 31;
    const int rbase = (lane >> 5) * 32;
    if (wave == 0) {
        #pragma unroll
        for (int i = 0; i < 10; ++i)
            w1r[i] = W1[i * 64 + lane];
        b1r = b1[lane];
        #pragma unroll
        for (int r = 0; r < 32; ++r)
            w2r[r] = W2[(rbase + r) * 32 + col];
        // BUGFIX vs R4: bias must be counted ONCE across the two lane halves
        // (acc2 halves are summed via shfl_down(32) — R4 added b2 twice).
        b2r = (lane < 32) ? b2[col] : 0.0f;
    }

    const float4* __restrict__ src =
        (const float4*)(points + (size_t)b * NPTS * 2);

    // ---- pass 1: global -> LDS stage + moment/minmax accumulation ----
    float minx =  INFINITY, miny =  INFINITY;
    float maxx = -INFINITY, maxy = -INFINITY;
    float sx = 0.f, sy = 0.f, sxx = 0.f, syy = 0.f;

    #pragma unroll
    for (int i = 0; i < ITERS; ++i) {
        const int idx = tid + i * BLOCK;
        float4 v = src[idx];
        pts[idx] = v;
        minx = fminf(minx, fminf(v.x, v.z));
        maxx = fmaxf(maxx, fmaxf(v.x, v.z));
        miny = fminf(miny, fminf(v.y, v.w));
        maxy = fmaxf(maxy, fmaxf(v.y, v.w));
        sx += v.x + v.z;
        sy += v.y + v.w;
        sxx = fmaf(v.x, v.x, sxx); sxx = fmaf(v.z, v.z, sxx);
        syy = fmaf(v.y, v.y, syy); syy = fmaf(v.w, v.w, syy);
    }

    // wave (64-lane) butterfly reduction
    #pragma unroll
    for (int off = 32; off > 0; off >>= 1) {
        minx = fminf(minx, __shfl_down(minx, off));
        maxx = fmaxf(maxx, __shfl_down(maxx, off));
        miny = fminf(miny, __shfl_down(miny, off));
        maxy = fmaxf(maxy, __shfl_down(maxy, off));
        sx  += __shfl_down(sx,  off);
        sy  += __shfl_down(sy,  off);
        sxx += __shfl_down(sxx, off);
        syy += __shfl_down(syy, off);
    }
    if (lane == 0) {
        wred[wave][0] = minx; wred[wave][1] = maxx;
        wred[wave][2] = miny; wred[wave][3] = maxy;
        wred[wave][4] = sx;   wred[wave][5] = sy;
        wred[wave][6] = sxx;  wred[wave][7] = syy;
    }
    __syncthreads();

    // pass 2 needs ONLY the centroid — everything else combined in epilogue
    const float invN = 1.0f / (float)NPTS;
    const float cx = ((wred[0][4] + wred[1][4]) + (wred[2][4] + wred[3][4])) * invN;
    const float cy = ((wred[0][5] + wred[1][5]) + (wred[2][5] + wred[3][5])) * invN;

    // ---- pass 2: sum of distances from LDS (sum(d^2) is analytic) ----
    float sd = 0.f;
    #pragma unroll
    for (int i = 0; i < ITERS; ++i) {
        float4 v = pts[tid + i * BLOCK];
        float dx0 = v.x - cx, dy0 = v.y - cy;
        float dx1 = v.z - cx, dy1 = v.w - cy;
        sd += sqrtf(fmaf(dx0, dx0, dy0 * dy0));
        sd += sqrtf(fmaf(dx1, dx1, dy1 * dy1));
    }
    #pragma unroll
    for (int off = 32; off > 0; off >>= 1)
        sd += __shfl_down(sd, off);
    if (lane == 0)
        wred[wave][8] = sd;
    __syncthreads();

    // ---- epilogue: wave 0 only, wave-synchronous (waves 1-3 retire) ----
    if (wave == 0) {
        float fminx = fminf(fminf(wred[0][0], wred[1][0]), fminf(wred[2][0], wred[3][0]));
        float fmaxx = fmaxf(fmaxf(wred[0][1], wred[1][1]), fmaxf(wred[2][1], wred[3][1]));
        float fminy = fminf(fminf(wred[0][2], wred[1][2]), fminf(wred[2][2], wred[3][2]));
        float fmaxy = fmaxf(fmaxf(wred[0][3], wred[1][3]), fmaxf(wred[2][3], wred[3][3]));
        float fsxx = (wred[0][6] + wred[1][6]) + (wred[2][6] + wred[3][6]);
        float fsyy = (wred[0][7] + wred[1][7]) + (wred[2][7] + wred[3][7]);
        float fsd  = (wred[0][8] + wred[1][8]) + (wred[2][8] + wred[3][8]);

        float dist_mean = fsd * invN;
        float ed2 = (fsxx + fsyy) * invN - (cx * cx + cy * cy);  // E[d^2]
        float dist_std  = sqrtf(fmaxf(ed2 - dist_mean * dist_mean, 0.f));
        float stdx = sqrtf(fmaxf(fsxx * invN - cx * cx, 0.f));
        float stdy = sqrtf(fmaxf(fsyy * invN - cy * cy, 0.f));

        float g[10];
        g[0] = (fminx + fmaxx) * 0.5f;   // bbox_center.x
        g[1] = (fminy + fmaxy) * 0.5f;   // bbox_center.y
        g[2] = fmaxx - fminx;            // bbox_size.x
        g[3] = fmaxy - fminy;            // bbox_size.y
        g[4] = cx;                       // centroid.x
        g[5] = cy;                       // centroid.y
        g[6] = stdx;                     // std.x
        g[7] = stdy;                     // std.y
        g[8] = dist_mean;
        g[9] = dist_std;

        // layer 1: lane l -> hidden unit l (weights already in registers)
        float acc = b1r;
        #pragma unroll
        for (int i = 0; i < 10; ++i)
            acc = fmaf(g[i], w1r[i], acc);
        h[lane] = fmaxf(acc, 0.f);

        // same-wave LDS write->read: drain LDS queue, block reordering
        asm volatile("s_waitcnt lgkmcnt(0)" ::: "memory");

        // layer 2: lane l -> col l&31, rows rbase..rbase+31 from registers
        float acc2 = b2r;
        #pragma unroll
        for (int r = 0; r < 32; ++r)
            acc2 = fmaf(h[rbase + r], w2r[r], acc2);
        acc2 += __shfl_down(acc2, 32);   // add rows 32..63 partial
        if (lane < 32)
            out[(size_t)b * 32 + lane] = fmaxf(acc2, 0.f);
    }
}

extern "C" void kernel_launch(void* const* d_in, const int* in_sizes, int n_in,
                              void* d_out, int out_size, void* d_ws, size_t ws_size,
                              hipStream_t stream) {
    const float* points = (const float*)d_in[0];
    const float* W1     = (const float*)d_in[1];
    const float* b1     = (const float*)d_in[2];
    const float* W2     = (const float*)d_in[3];
    const float* b2     = (const float*)d_in[4];
    float* out          = (float*)d_out;

    const int B = in_sizes[0] / (NPTS * 2);   // 4096
    geo_mlp_kernel<<<B, BLOCK, 0, stream>>>(points, W1, b1, W2, b2, out);
}